// Round 5
// baseline (158.557 us; speedup 1.0000x reference)
//
#include <hip/hip_runtime.h>

// DmvCell RNN scan, B=32, T=2048, D=512. out[b][t] = [mean|var|max] (3*D).
// Compulsory traffic: 128 MB in + 402 MB out.
//
// R5 = R4 with ONE change: scan's output uses REGULAR streaming stores
// instead of nontemporal (A/B test: fillBuffer proves regular full-line
// streaming stores hit 7 TB/s on this chip; nt was the unproven element).
//
// Structure: per-wave SEQUENTIAL streams. A wave owns (batch b, T-chunk c)
// and ALL of D: input stream = CHUNK x 2KB linear, output stream =
// CHUNK x 6KB linear (6 float4 stores/step, gapless). Lane l carries 8
// chains: d in {4l..4l+3} u {256+4l..256+4l+3}.
//  1) agg:   per (b,c) wave -> (sum, M2, max) per chain into d_ws (cached)
//  2) prefix: per float-chain serial fold over NC chunks (parallel-variance
//             merge); exact carry stored in place
//  3) scan:  load carry, exact sequential rescan, streaming stores.
// NC=128 -> 4096 waves (16/CU). Fallback ladder NC=64/32, then proven R2.

#define BB 32
#define TT 2048
#define DD 512
#define NCHAIN (BB * DD)          // 16384 float chains
#define NF4PERB 128               // float4 per row (512 floats)

typedef float f32x4 __attribute__((ext_vector_type(4)));

__device__ __forceinline__ float fast_rcp(float x) {
#if __has_builtin(__builtin_amdgcn_rcpf)
    return __builtin_amdgcn_rcpf(x);
#else
    return 1.0f / x;
#endif
}

__device__ __forceinline__ f32x4 vmax4(f32x4 a, f32x4 b) {
#if __has_builtin(__builtin_elementwise_max)
    return __builtin_elementwise_max(a, b);
#else
    f32x4 r;
    r.x = fmaxf(a.x, b.x); r.y = fmaxf(a.y, b.y);
    r.z = fmaxf(a.z, b.z); r.w = fmaxf(a.w, b.w);
    return r;
#endif
}

// R5: regular streaming store (was __builtin_nontemporal_store in R4)
__device__ __forceinline__ void sts(f32x4 v, float* p) {
    *(f32x4*)p = v;
}

// ---------------- kernel 1: per-chunk aggregates (sequential reads) --------
template <int NC>
__launch_bounds__(256)
__global__ void dmv_agg_kernel(const float* __restrict__ x,
                               f32x4* __restrict__ ws4) {
    constexpr int CHUNK = TT / NC;
    f32x4* __restrict__ aS  = ws4;
    f32x4* __restrict__ aM2 = ws4 + (size_t)NC * 4096;
    f32x4* __restrict__ aMX = ws4 + 2 * (size_t)NC * 4096;

    const int tid = blockIdx.x * 256 + threadIdx.x;
    const int W   = tid >> 6;
    const int l   = tid & 63;
    const int c   = W & (NC - 1);
    const int b   = W / NC;

    const float* xp = x + ((size_t)(b * TT + c * CHUNK)) * DD + 4 * l;

    f32x4 s0 = {0,0,0,0}, s1 = {0,0,0,0};
    f32x4 q0 = {0,0,0,0}, q1 = {0,0,0,0};
    f32x4 m0 = {0,0,0,0}, m1 = {0,0,0,0};
    #pragma unroll 4
    for (int k = 0; k < CHUNK; ++k) {
        f32x4 a = *(const f32x4*)(xp + (size_t)k * DD);
        f32x4 b2 = *(const f32x4*)(xp + (size_t)k * DD + 256);
        s0 += a;  q0 += a * a;   m0 = vmax4(m0, a);
        s1 += b2; q1 += b2 * b2; m1 = vmax4(m1, b2);
    }
    const size_t o = (size_t)c * 4096 + (size_t)b * NF4PERB + l;
    const float ic = 1.0f / (float)CHUNK;
    aS[o]       = s0;  aS[o + 64]  = s1;
    aM2[o]      = q0 - s0 * s0 * ic;
    aM2[o + 64] = q1 - s1 * s1 * ic;
    aMX[o]      = m0;  aMX[o + 64] = m1;
}

// ---------------- kernel 2: in-place prefix fold (per float chain) ---------
template <int NC>
__launch_bounds__(256)
__global__ void dmv_prefix_kernel(float* __restrict__ ws) {
    constexpr int CHUNK = TT / NC;
    float* __restrict__ aS  = ws;
    float* __restrict__ aM2 = ws + (size_t)NC * NCHAIN;
    float* __restrict__ aMX = ws + 2 * (size_t)NC * NCHAIN;

    const int i = blockIdx.x * 256 + threadIdx.x;  // float chain b*512+d

    // c = 0 peeled: carry before chunk 0 is the zero state
    float rs = aS[i], rm2 = aM2[i], rmx = aMX[i];
    aS[i] = 0.f; aM2[i] = 0.f; aMX[i] = 0.f;
    float rn = (float)CHUNK;
    #pragma unroll 8
    for (int c = 1; c < NC; ++c) {
        const size_t idx = (size_t)c * NCHAIN + i;
        float ts = aS[idx], tm2 = aM2[idx], tmx = aMX[idx];
        aS[idx] = rs; aM2[idx] = rm2; aMX[idx] = rmx;   // carry for chunk c
        float n  = rn + (float)CHUNK;
        float da = ts * (1.f / CHUNK) - rs / rn;
        rm2 = rm2 + tm2 + da * da * (rn * (float)CHUNK / n);
        rs += ts;
        rmx = fmaxf(rmx, tmx);
        rn  = n;
    }
}

// ---------------- kernel 3: rescan, sequential streaming stores ------------
template <int NC>
__launch_bounds__(256)
__global__ void dmv_scan_kernel3(const float* __restrict__ x,
                                 const f32x4* __restrict__ ws4,
                                 float* __restrict__ out) {
    constexpr int CHUNK = TT / NC;
    const f32x4* __restrict__ aS  = ws4;
    const f32x4* __restrict__ aM2 = ws4 + (size_t)NC * 4096;
    const f32x4* __restrict__ aMX = ws4 + 2 * (size_t)NC * 4096;

    const int tid = blockIdx.x * 256 + threadIdx.x;
    const int W   = tid >> 6;
    const int l   = tid & 63;
    const int c   = W & (NC - 1);
    const int b   = W / NC;

    const size_t o = (size_t)c * 4096 + (size_t)b * NF4PERB + l;
    f32x4 rs0 = aS[o],  rs1 = aS[o + 64];
    f32x4 rm20 = aM2[o], rm21 = aM2[o + 64];
    f32x4 rmx0 = aMX[o], rmx1 = aMX[o + 64];

    float cnt = (float)(c * CHUNK);
    f32x4 rmean0 = {0,0,0,0}, rmean1 = {0,0,0,0};
    if (c > 0) {
        float icnt = fast_rcp(cnt);
        rmean0 = rs0 * icnt;
        rmean1 = rs1 * icnt;
    }

    const float* xp = x   + ((size_t)(b * TT + c * CHUNK)) * DD + 4 * l;
    float*       op = out + ((size_t)(b * TT + c * CHUNK)) * (3 * DD) + 4 * l;

    #pragma unroll 4
    for (int k = 0; k < CHUNK; ++k) {
        f32x4 v0 = *(const f32x4*)(xp + (size_t)k * DD);
        f32x4 v1 = *(const f32x4*)(xp + (size_t)k * DD + 256);
        cnt += 1.f;
        float inv = fast_rcp(cnt);
        rs0 += v0; rs1 += v1;
        rmx0 = vmax4(rmx0, v0); rmx1 = vmax4(rmx1, v1);
        f32x4 nm0 = rs0 * inv, nm1 = rs1 * inv;
        rm20 += (v0 - rmean0) * (v0 - nm0);
        rm21 += (v1 - rmean1) * (v1 - nm1);
        rmean0 = nm0; rmean1 = nm1;
        f32x4 var0 = rm20 * inv, var1 = rm21 * inv;
        float* row = op + (size_t)k * (3 * DD);
        sts(nm0,  row);        sts(nm1,  row + 256);
        sts(var0, row + 512);  sts(var1, row + 768);
        sts(rmx0, row + 1024); sts(rmx1, row + 1280);
    }
}

// ---------------- fallback (R2, proven): single kernel, LDS merge ----------
#define FNW 16
#define FCHUNK (TT / FNW)
#define DGRP 64

__launch_bounds__(1024, 1)
__global__ void dmv_scan_fallback(const float* __restrict__ x,
                                  float* __restrict__ out) {
    __shared__ float aggS[FNW][DGRP];
    __shared__ float aggM2[FNW][DGRP];
    __shared__ float aggMX[FNW][DGRP];

    const int tid = threadIdx.x;
    const int w   = tid >> 6;
    const int l   = tid & 63;
    const int b   = blockIdx.x >> 3;
    const int d0  = (blockIdx.x & 7) * DGRP;

    const float* xp = x   + ((size_t)b * TT) * DD + d0 + l
                          + (size_t)(w * FCHUNK) * DD;
    float*       op = out + ((size_t)b * TT) * (3 * DD) + d0 + l
                          + (size_t)(w * FCHUNK) * (3 * DD);

    if (w < FNW - 1) {
        float s = 0.f, ss = 0.f, mx = 0.f;
        #pragma unroll 8
        for (int k = 0; k < FCHUNK; ++k) {
            float xv = xp[(size_t)k * DD];
            s += xv; ss = fmaf(xv, xv, ss); mx = fmaxf(mx, xv);
        }
        aggS[w][l] = s;
        aggM2[w][l] = ss - s * s * (1.0f / FCHUNK);
        aggMX[w][l] = mx;
    }
    __syncthreads();

    float c_n = 0.f, c_s = 0.f, c_m2 = 0.f, c_mx = 0.f;
    for (int j = 0; j < w; ++j) {
        float bs = aggS[j][l], bm2 = aggM2[j][l], bmx = aggMX[j][l];
        if (j == 0) {
            c_n = (float)FCHUNK; c_s = bs; c_m2 = bm2; c_mx = bmx;
        } else {
            float n  = c_n + (float)FCHUNK;
            float da = bs * (1.0f / FCHUNK) - c_s / c_n;
            c_m2 = c_m2 + bm2 + da * da * (c_n * (float)FCHUNK / n);
            c_s += bs; c_mx = fmaxf(c_mx, bmx); c_n = n;
        }
    }

    float cnt = c_n, rs = c_s, rm2 = c_m2, rmx = c_mx;
    float rmean = (w > 0) ? rs / cnt : 0.f;
    #pragma unroll 8
    for (int k = 0; k < FCHUNK; ++k) {
        float xv = xp[(size_t)k * DD];
        cnt += 1.f;
        float inv = fast_rcp(cnt);
        rs += xv; rmx = fmaxf(rmx, xv);
        float nm = rs * inv;
        rm2 += (xv - rmean) * (xv - nm);
        rmean = nm;
        float var = rm2 * inv;
        float* orow = op + (size_t)k * (3 * DD);
        orow[0] = nm; orow[DD] = var; orow[2 * DD] = rmx;
    }
}

// ---------------- launcher ----------------
template <int NC>
static void launch_3k(const float* x, float* out, void* d_ws, hipStream_t stream) {
    dim3 blk(256);
    // agg & scan: 32*NC waves -> 8*NC blocks of 256
    dmv_agg_kernel<NC><<<dim3(8 * NC), blk, 0, stream>>>(x, (f32x4*)d_ws);
    dmv_prefix_kernel<NC><<<dim3(NCHAIN / 256), blk, 0, stream>>>((float*)d_ws);
    dmv_scan_kernel3<NC><<<dim3(8 * NC), blk, 0, stream>>>(x, (const f32x4*)d_ws, out);
}

extern "C" void kernel_launch(void* const* d_in, const int* in_sizes, int n_in,
                              void* d_out, int out_size, void* d_ws, size_t ws_size,
                              hipStream_t stream) {
    (void)in_sizes; (void)n_in; (void)out_size;
    const float* x = (const float*)d_in[0];
    float* out = (float*)d_out;

    const size_t need128 = (size_t)3 * 128 * NCHAIN * sizeof(float);  // 25.2 MB
    const size_t need64  = (size_t)3 * 64  * NCHAIN * sizeof(float);  // 12.6 MB
    const size_t need32  = (size_t)3 * 32  * NCHAIN * sizeof(float);  //  6.3 MB

    if (d_ws && ws_size >= need128) {
        launch_3k<128>(x, out, d_ws, stream);
    } else if (d_ws && ws_size >= need64) {
        launch_3k<64>(x, out, d_ws, stream);
    } else if (d_ws && ws_size >= need32) {
        launch_3k<32>(x, out, d_ws, stream);
    } else {
        dmv_scan_fallback<<<dim3(BB * (DD / DGRP)), dim3(1024), 0, stream>>>(x, out);
    }
}

// Round 6
// 121.833 us; speedup vs baseline: 1.3014x; 1.3014x over previous
//
#include <hip/hip_runtime.h>

// DmvCell RNN scan, B=32, T=2048, D=512. out[b][t] = [mean|var|max] (3*D).
// Compulsory traffic: 128 MB in + 402 MB out.
//
// R6 = R4 minus the prefix kernel: TWO kernels.
//  1) agg:  wave (b,c) streams its CHUNK x 2KB linear slice, computes
//           (sum, M2, max) per chain -> 12.6 MB table in d_ws (L2-resident).
//  2) scan: wave (b,c) folds aggs[0..c) straight from L2 (Welford merge is
//           commutative+associative; ~390 MB of L2 reads total, ~11 us,
//           overlapped), then rescans its chunk (x is L3-resident; output
//           NONTEMPORAL stores don't evict it - proven R4 vs R5 A/B) and
//           streams CHUNK x 6KB linear nt-stores.
// NC=64 -> 2048 waves (8/CU). Fallback NC=32, then proven R2 single-kernel.

#define BB 32
#define TT 2048
#define DD 512
#define NCHAIN (BB * DD)          // 16384 float chains
#define NF4PERB 128               // float4 per row (512 floats)

typedef float f32x4 __attribute__((ext_vector_type(4)));

__device__ __forceinline__ float fast_rcp(float x) {
#if __has_builtin(__builtin_amdgcn_rcpf)
    return __builtin_amdgcn_rcpf(x);
#else
    return 1.0f / x;
#endif
}

__device__ __forceinline__ f32x4 vmax4(f32x4 a, f32x4 b) {
#if __has_builtin(__builtin_elementwise_max)
    return __builtin_elementwise_max(a, b);
#else
    f32x4 r;
    r.x = fmaxf(a.x, b.x); r.y = fmaxf(a.y, b.y);
    r.z = fmaxf(a.z, b.z); r.w = fmaxf(a.w, b.w);
    return r;
#endif
}

__device__ __forceinline__ void nts(f32x4 v, float* p) {
#if __has_builtin(__builtin_nontemporal_store)
    __builtin_nontemporal_store(v, (f32x4*)p);
#else
    *(f32x4*)p = v;
#endif
}

// ---------------- kernel 1: per-chunk aggregates (sequential reads) --------
template <int NC>
__launch_bounds__(256)
__global__ void dmv_agg_kernel(const float* __restrict__ x,
                               f32x4* __restrict__ ws4) {
    constexpr int CHUNK = TT / NC;
    f32x4* __restrict__ aS  = ws4;
    f32x4* __restrict__ aM2 = ws4 + (size_t)NC * 4096;
    f32x4* __restrict__ aMX = ws4 + 2 * (size_t)NC * 4096;

    const int tid = blockIdx.x * 256 + threadIdx.x;
    const int W   = tid >> 6;
    const int l   = tid & 63;
    const int c   = W & (NC - 1);
    const int b   = W / NC;

    const float* xp = x + ((size_t)(b * TT + c * CHUNK)) * DD + 4 * l;

    f32x4 s0 = {0,0,0,0}, s1 = {0,0,0,0};
    f32x4 q0 = {0,0,0,0}, q1 = {0,0,0,0};
    f32x4 m0 = {0,0,0,0}, m1 = {0,0,0,0};
    #pragma unroll 4
    for (int k = 0; k < CHUNK; ++k) {
        f32x4 a  = *(const f32x4*)(xp + (size_t)k * DD);
        f32x4 b2 = *(const f32x4*)(xp + (size_t)k * DD + 256);
        s0 += a;  q0 += a * a;   m0 = vmax4(m0, a);
        s1 += b2; q1 += b2 * b2; m1 = vmax4(m1, b2);
    }
    const size_t o = (size_t)c * 4096 + (size_t)b * NF4PERB + l;
    const float ic = 1.0f / (float)CHUNK;
    aS[o]       = s0;  aS[o + 64]  = s1;
    aM2[o]      = q0 - s0 * s0 * ic;
    aM2[o + 64] = q1 - s1 * s1 * ic;
    aMX[o]      = m0;  aMX[o + 64] = m1;
}

// ---------------- kernel 2: fused prefix-fold + rescan + nt stores ---------
template <int NC>
__launch_bounds__(256)
__global__ void dmv_scan_fused(const float* __restrict__ x,
                               const f32x4* __restrict__ ws4,
                               float* __restrict__ out) {
    constexpr int CHUNK = TT / NC;
    const f32x4* __restrict__ aS  = ws4;
    const f32x4* __restrict__ aM2 = ws4 + (size_t)NC * 4096;
    const f32x4* __restrict__ aMX = ws4 + 2 * (size_t)NC * 4096;

    const int tid = blockIdx.x * 256 + threadIdx.x;
    const int W   = tid >> 6;
    const int l   = tid & 63;
    const int c   = W & (NC - 1);
    const int b   = W / NC;

    // ---- exclusive prefix over chunks [0, c): fold from L2-resident table.
    f32x4 rs0 = {0,0,0,0}, rs1 = {0,0,0,0};
    f32x4 rm20 = {0,0,0,0}, rm21 = {0,0,0,0};
    f32x4 rmx0 = {0,0,0,0}, rmx1 = {0,0,0,0};
    float rn = 0.f;
    if (c > 0) {
        const size_t o0 = (size_t)b * NF4PERB + l;
        rs0  = aS[o0];  rs1  = aS[o0 + 64];
        rm20 = aM2[o0]; rm21 = aM2[o0 + 64];
        rmx0 = aMX[o0]; rmx1 = aMX[o0 + 64];
        rn = (float)CHUNK;
        for (int j = 1; j < c; ++j) {
            const size_t oj = (size_t)j * 4096 + (size_t)b * NF4PERB + l;
            f32x4 ts0 = aS[oj],  ts1 = aS[oj + 64];
            f32x4 tm0 = aM2[oj], tm1 = aM2[oj + 64];
            f32x4 tx0 = aMX[oj], tx1 = aMX[oj + 64];
            float n     = rn + (float)CHUNK;
            float irn   = fast_rcp(rn);
            float scale = rn * (float)CHUNK * fast_rcp(n);
            f32x4 da0 = ts0 * (1.0f / CHUNK) - rs0 * irn;
            f32x4 da1 = ts1 * (1.0f / CHUNK) - rs1 * irn;
            rm20 += tm0 + da0 * da0 * scale;
            rm21 += tm1 + da1 * da1 * scale;
            rs0 += ts0; rs1 += ts1;
            rmx0 = vmax4(rmx0, tx0); rmx1 = vmax4(rmx1, tx1);
            rn = n;
        }
    }

    float cnt = rn;  // == c * CHUNK
    f32x4 rmean0 = {0,0,0,0}, rmean1 = {0,0,0,0};
    if (c > 0) {
        float icnt = fast_rcp(cnt);
        rmean0 = rs0 * icnt;
        rmean1 = rs1 * icnt;
    }

    // ---- exact sequential rescan of own chunk; nt-store output streams ----
    const float* xp = x   + ((size_t)(b * TT + c * CHUNK)) * DD + 4 * l;
    float*       op = out + ((size_t)(b * TT + c * CHUNK)) * (3 * DD) + 4 * l;

    #pragma unroll 4
    for (int k = 0; k < CHUNK; ++k) {
        f32x4 v0 = *(const f32x4*)(xp + (size_t)k * DD);
        f32x4 v1 = *(const f32x4*)(xp + (size_t)k * DD + 256);
        cnt += 1.f;
        float inv = fast_rcp(cnt);
        rs0 += v0; rs1 += v1;
        rmx0 = vmax4(rmx0, v0); rmx1 = vmax4(rmx1, v1);
        f32x4 nm0 = rs0 * inv, nm1 = rs1 * inv;
        rm20 += (v0 - rmean0) * (v0 - nm0);
        rm21 += (v1 - rmean1) * (v1 - nm1);
        rmean0 = nm0; rmean1 = nm1;
        f32x4 var0 = rm20 * inv, var1 = rm21 * inv;
        float* row = op + (size_t)k * (3 * DD);
        nts(nm0,  row);        nts(nm1,  row + 256);
        nts(var0, row + 512);  nts(var1, row + 768);
        nts(rmx0, row + 1024); nts(rmx1, row + 1280);
    }
}

// ---------------- fallback (R2, proven): single kernel, LDS merge ----------
#define FNW 16
#define FCHUNK (TT / FNW)
#define DGRP 64

__launch_bounds__(1024, 1)
__global__ void dmv_scan_fallback(const float* __restrict__ x,
                                  float* __restrict__ out) {
    __shared__ float aggS[FNW][DGRP];
    __shared__ float aggM2[FNW][DGRP];
    __shared__ float aggMX[FNW][DGRP];

    const int tid = threadIdx.x;
    const int w   = tid >> 6;
    const int l   = tid & 63;
    const int b   = blockIdx.x >> 3;
    const int d0  = (blockIdx.x & 7) * DGRP;

    const float* xp = x   + ((size_t)b * TT) * DD + d0 + l
                          + (size_t)(w * FCHUNK) * DD;
    float*       op = out + ((size_t)b * TT) * (3 * DD) + d0 + l
                          + (size_t)(w * FCHUNK) * (3 * DD);

    if (w < FNW - 1) {
        float s = 0.f, ss = 0.f, mx = 0.f;
        #pragma unroll 8
        for (int k = 0; k < FCHUNK; ++k) {
            float xv = xp[(size_t)k * DD];
            s += xv; ss = fmaf(xv, xv, ss); mx = fmaxf(mx, xv);
        }
        aggS[w][l] = s;
        aggM2[w][l] = ss - s * s * (1.0f / FCHUNK);
        aggMX[w][l] = mx;
    }
    __syncthreads();

    float c_n = 0.f, c_s = 0.f, c_m2 = 0.f, c_mx = 0.f;
    for (int j = 0; j < w; ++j) {
        float bs = aggS[j][l], bm2 = aggM2[j][l], bmx = aggMX[j][l];
        if (j == 0) {
            c_n = (float)FCHUNK; c_s = bs; c_m2 = bm2; c_mx = bmx;
        } else {
            float n  = c_n + (float)FCHUNK;
            float da = bs * (1.0f / FCHUNK) - c_s / c_n;
            c_m2 = c_m2 + bm2 + da * da * (c_n * (float)FCHUNK / n);
            c_s += bs; c_mx = fmaxf(c_mx, bmx); c_n = n;
        }
    }

    float cnt = c_n, rs = c_s, rm2 = c_m2, rmx = c_mx;
    float rmean = (w > 0) ? rs / cnt : 0.f;
    #pragma unroll 8
    for (int k = 0; k < FCHUNK; ++k) {
        float xv = xp[(size_t)k * DD];
        cnt += 1.f;
        float inv = fast_rcp(cnt);
        rs += xv; rmx = fmaxf(rmx, xv);
        float nm = rs * inv;
        rm2 += (xv - rmean) * (xv - nm);
        rmean = nm;
        float var = rm2 * inv;
        float* orow = op + (size_t)k * (3 * DD);
        orow[0] = nm; orow[DD] = var; orow[2 * DD] = rmx;
    }
}

// ---------------- launcher ----------------
template <int NC>
static void launch_2k(const float* x, float* out, void* d_ws, hipStream_t stream) {
    dim3 blk(256);
    // 32*NC waves -> 8*NC blocks of 256 (4 waves each)
    dmv_agg_kernel<NC><<<dim3(8 * NC), blk, 0, stream>>>(x, (f32x4*)d_ws);
    dmv_scan_fused<NC><<<dim3(8 * NC), blk, 0, stream>>>(x, (const f32x4*)d_ws, out);
}

extern "C" void kernel_launch(void* const* d_in, const int* in_sizes, int n_in,
                              void* d_out, int out_size, void* d_ws, size_t ws_size,
                              hipStream_t stream) {
    (void)in_sizes; (void)n_in; (void)out_size;
    const float* x = (const float*)d_in[0];
    float* out = (float*)d_out;

    const size_t need64 = (size_t)3 * 64 * NCHAIN * sizeof(float);  // 12.6 MB
    const size_t need32 = (size_t)3 * 32 * NCHAIN * sizeof(float);  //  6.3 MB

    if (d_ws && ws_size >= need64) {
        launch_2k<64>(x, out, d_ws, stream);
    } else if (d_ws && ws_size >= need32) {
        launch_2k<32>(x, out, d_ws, stream);
    } else {
        dmv_scan_fallback<<<dim3(BB * (DD / DGRP)), dim3(1024), 0, stream>>>(x, out);
    }
}